// Round 8
// baseline (711.025 us; speedup 1.0000x reference)
//
#include <hip/hip_runtime.h>
#include <hip/hip_bf16.h>

typedef unsigned short u16;
typedef __attribute__((ext_vector_type(4))) float f32x4;
typedef __attribute__((ext_vector_type(8))) short bf16x8;

// ---------------------------------------------------------------------------
// helpers
// ---------------------------------------------------------------------------
__device__ __forceinline__ u16 f2bf(float f) {
    union { float f; unsigned u; } v; v.f = f;
    unsigned r = (v.u + 0x7fffu + ((v.u >> 16) & 1u)) >> 16;   // RNE
    return (u16)r;
}

__device__ __forceinline__ float softplus(float x) {
    return (x > 15.f) ? x : log1pf(__expf(x));
}

__device__ __forceinline__ void gload_lds16(const void* g, void* l) {
    __builtin_amdgcn_global_load_lds(
        (__attribute__((address_space(1))) void*)(g),
        (__attribute__((address_space(3))) void*)(l),
        16, 0, 0);
}

#define BAR() do { asm volatile("" ::: "memory"); \
                   __builtin_amdgcn_s_barrier();  \
                   asm volatile("" ::: "memory"); } while (0)

// ---------------------------------------------------------------------------
// fused prep: x->bf16, W = mu + softplus(rho)*eps -> bf16, bias (f32)
// ---------------------------------------------------------------------------
__global__ __launch_bounds__(256) void prep_all(
        const float* __restrict__ x,
        const float* __restrict__ wmu, const float* __restrict__ wrho,
        const float* __restrict__ ew,
        const float* __restrict__ bmu, const float* __restrict__ brho,
        const float* __restrict__ eb,
        u16* __restrict__ xb, u16* __restrict__ wb, float* __restrict__ bs,
        int nx4, int nw4, int nb) {
    int i = blockIdx.x * 256 + threadIdx.x;
    if (i < nx4) {
        float4 v = ((const float4*)x)[i];
        ushort4 o;
        o.x = f2bf(v.x); o.y = f2bf(v.y); o.z = f2bf(v.z); o.w = f2bf(v.w);
        ((ushort4*)xb)[i] = o;
    }
    if (i < nw4) {
        float4 m = ((const float4*)wmu)[i];
        float4 r = ((const float4*)wrho)[i];
        float4 e = ((const float4*)ew)[i];
        ushort4 o;
        o.x = f2bf(m.x + softplus(r.x) * e.x);
        o.y = f2bf(m.y + softplus(r.y) * e.y);
        o.z = f2bf(m.z + softplus(r.z) * e.z);
        o.w = f2bf(m.w + softplus(r.w) * e.w);
        ((ushort4*)wb)[i] = o;
    }
    if (i < nb) {
        bs[i] = bmu[i] + softplus(brho[i]) * eb[i];
    }
}

// ---------------------------------------------------------------------------
// 256x128 tile, BK=32, 2 blocks/CU bf16 GEMM (B^T) + bias.
// 8 waves (4m x 2n), per-wave 64x64 (acc[4][4] f32x4 = 64 regs).
// LDS 48 KiB: A 2x[256][32], B 2x[128][32] bf16. Chunk layout per 16-row
// subtile: phys_kc = (kc + row) & 3 (row-rotation -> service groups walk all
// 8 bank-quads; linear layout measured 6.7e7 conflicts in round 1).
// DMA: dest linear (wave base + lane*16), source pre-applies inverse rotation.
// 2 phases/K-tile (mi-halves, B held in regs); vmcnt(1) at PH2/PH4 BEFORE the
// mid-barrier => wait -> barrier -> read chain for every buffer.
// ---------------------------------------------------------------------------
#define STAGE_A(regionC, h, k0) \
    gload_lds16(pA[h] + (k0), (char*)(regionC) + (h) * 8192 + w * 1024)
#define STAGE_B(regionC, k0) \
    gload_lds16(pB + (k0), (char*)(regionC) + w * 1024)

#define RD_A2(regC, mi0)                                              \
    do {                                                              \
        a[0] = *(const bf16x8*)((const char*)(regC) + aboff + (wr * 64 + (mi0) * 16) * 64);      \
        a[1] = *(const bf16x8*)((const char*)(regC) + aboff + (wr * 64 + (mi0) * 16 + 16) * 64); \
    } while (0)

#define RD_B4(regC)                                                   \
    do {                                                              \
        b[0] = *(const bf16x8*)((const char*)(regC) + aboff + (wc * 64 +  0) * 64); \
        b[1] = *(const bf16x8*)((const char*)(regC) + aboff + (wc * 64 + 16) * 64); \
        b[2] = *(const bf16x8*)((const char*)(regC) + aboff + (wc * 64 + 32) * 64); \
        b[3] = *(const bf16x8*)((const char*)(regC) + aboff + (wc * 64 + 48) * 64); \
    } while (0)

template <int MB>
__device__ __forceinline__ void mfma8(f32x4 (&acc)[4][4],
                                      const bf16x8 (&a)[2],
                                      const bf16x8 (&b)[4]) {
#pragma unroll
    for (int mi = 0; mi < 2; ++mi)
#pragma unroll
        for (int ni = 0; ni < 4; ++ni)
            acc[MB + mi][ni] = __builtin_amdgcn_mfma_f32_16x16x32_bf16(
                a[mi], b[ni], acc[MB + mi][ni], 0, 0, 0);
}

__global__ __launch_bounds__(512, 4) void gemm_bk32(
        const u16* __restrict__ A,   // [M][K] bf16
        const u16* __restrict__ B,   // [Nout][K] bf16
        const float* __restrict__ bias,
        float* __restrict__ C,       // [M][Nout] fp32
        int M, int Nout, int K) {
    __shared__ __attribute__((aligned(16))) u16 smem[24576];  // 48 KiB
    char* A0c = (char*)smem;            // 16 KiB  [256][32]
    char* A1c = (char*)smem + 16384;    // 16 KiB
    char* B0c = (char*)smem + 32768;    //  8 KiB  [128][32]
    char* B1c = (char*)smem + 40960;    //  8 KiB

    const int tid  = threadIdx.x;
    const int lane = tid & 63;
    const int w    = tid >> 6;     // wave 0..7
    const int wr   = w >> 1;       // 0..3 -> 64-row slice
    const int wc   = w & 1;        // 0..1 -> 64-col slice

    // bijective XCD swizzle (nwg = 2048, %8 == 0)
    const int nbn = Nout >> 7;                  // 32
    const int nwg = (M >> 8) * nbn;             // 2048
    const int cpx = nwg >> 3;
    const int swz = ((int)blockIdx.x & 7) * cpx + ((int)blockIdx.x >> 3);
    const int m0 = (swz / nbn) << 8;
    const int n0 = (swz % nbn) << 7;

    // ---- staging source pointers (inverse of the row-rotation layout) ----
    // thread (w,lane) writes phys slot lane*16 in subtile w:
    //   r = lane>>2, kc_phys = lane&3, logical kc = (kc_phys - r) & 3
    const int rS  = w * 16 + (lane >> 2);
    const int kcl = ((lane & 3) - (lane >> 2)) & 3;
    const u16* pA[2];
    pA[0] = A + (size_t)(m0 + rS) * K + kcl * 8;
    pA[1] = pA[0] + (size_t)128 * K;
    const u16* pB = B + (size_t)(n0 + rS) * K + kcl * 8;

    // ---- fragment-read per-thread byte offset (r0 = 0 base) ----
    // logical (row = r0+(lane&15), kc = lane>>4); phys kc = (kc+row)&3
    const int kq    = ((lane >> 4) + (lane & 3)) & 3;
    const int aboff = (lane & 15) * 64 + kq * 16;

    bf16x8 a[2], b[4];
    f32x4 acc[4][4] = {};

    const int NT = K >> 5;    // 128 K-tiles
    const int NI = NT >> 1;   // 64 iterations (2 tiles each)

    // prologue: B0(t0), A0(t0) both halves, B1(t1); vmcnt(1) leaves B1 flying
    STAGE_B(B0c, 0);
    STAGE_A(A0c, 0, 0); STAGE_A(A0c, 1, 0);
    STAGE_B(B1c, 32);
    asm volatile("s_waitcnt vmcnt(1)" ::: "memory");
    BAR();

#pragma unroll 1
    for (int i = 0; i < NI; ++i) {
        int t2 = 2 * i + 2; if (t2 >= NT) t2 -= NT;
        int t3 = 2 * i + 3; if (t3 >= NT) t3 -= NT;
        const int k1 = (2 * i + 1) << 5;
        const int k2 = t2 << 5;
        const int k3 = t3 << 5;

        // ---- PH1: t0 mi0-1 | rd A0(2)+B0(4) | stage A1 both halves (t1)
        RD_A2(A0c, 0);
        RD_B4(B0c);
        STAGE_A(A1c, 0, k1); STAGE_A(A1c, 1, k1);
        BAR();
        asm volatile("s_waitcnt lgkmcnt(0)" ::: "memory");
        __builtin_amdgcn_s_setprio(1);
        mfma8<0>(acc, a, b);
        __builtin_amdgcn_s_setprio(0);
        BAR();

        // ---- PH2: t0 mi2-3 | rd A0(2) | stage B0(t2) | vmcnt(1): t1 landed
        RD_A2(A0c, 2);
        STAGE_B(B0c, k2);
        asm volatile("s_waitcnt vmcnt(1)" ::: "memory");
        BAR();
        asm volatile("s_waitcnt lgkmcnt(0)" ::: "memory");
        __builtin_amdgcn_s_setprio(1);
        mfma8<2>(acc, a, b);
        __builtin_amdgcn_s_setprio(0);
        BAR();

        // ---- PH3: t1 mi0-1 | rd A1(2)+B1(4) | stage A0 both halves (t2)
        RD_A2(A1c, 0);
        RD_B4(B1c);
        STAGE_A(A0c, 0, k2); STAGE_A(A0c, 1, k2);
        BAR();
        asm volatile("s_waitcnt lgkmcnt(0)" ::: "memory");
        __builtin_amdgcn_s_setprio(1);
        mfma8<0>(acc, a, b);
        __builtin_amdgcn_s_setprio(0);
        BAR();

        // ---- PH4: t1 mi2-3 | rd A1(2) | stage B1(t3) | vmcnt(1): t2 landed
        RD_A2(A1c, 2);
        STAGE_B(B1c, k3);
        asm volatile("s_waitcnt vmcnt(1)" ::: "memory");
        BAR();
        asm volatile("s_waitcnt lgkmcnt(0)" ::: "memory");
        __builtin_amdgcn_s_setprio(1);
        mfma8<2>(acc, a, b);
        __builtin_amdgcn_s_setprio(0);
        BAR();
    }

    asm volatile("s_waitcnt vmcnt(0)" ::: "memory");  // drain wrapped prefetch

    // epilogue: C/D layout col = lane&15, row = (lane>>4)*4 + q; direct stores
    const int crow = (lane >> 4) * 4;
    const int ccol = lane & 15;
#pragma unroll
    for (int mi = 0; mi < 4; ++mi) {
#pragma unroll
        for (int ni = 0; ni < 4; ++ni) {
            const int row = m0 + wr * 64 + mi * 16 + crow;
            const int col = n0 + wc * 64 + ni * 16 + ccol;
            const float bv = bias[col];
            float* Cp = C + (size_t)row * Nout + col;
#pragma unroll
            for (int q = 0; q < 4; ++q)
                Cp[(size_t)q * Nout] = acc[mi][ni][q] + bv;
        }
    }
}

// ---------------------------------------------------------------------------
// launch
// ---------------------------------------------------------------------------
extern "C" void kernel_launch(void* const* d_in, const int* in_sizes, int n_in,
                              void* d_out, int out_size, void* d_ws, size_t ws_size,
                              hipStream_t stream) {
    const float* x    = (const float*)d_in[0];
    const float* wmu  = (const float*)d_in[1];
    const float* wrho = (const float*)d_in[2];
    const float* bmu  = (const float*)d_in[3];
    const float* brho = (const float*)d_in[4];
    const float* ew   = (const float*)d_in[5];
    const float* eb   = (const float*)d_in[6];
    float* out = (float*)d_out;

    const int Nout = in_sizes[3];            // 4096
    const int K    = in_sizes[1] / Nout;     // 4096
    const int M    = in_sizes[0] / K;        // 16384

    u16* xb = (u16*)d_ws;
    u16* wb = xb + (size_t)M * K;
    float* bs = (float*)(wb + (size_t)Nout * K);

    const int nx4 = (M * K) / 4;
    const int nw4 = (Nout * K) / 4;
    prep_all<<<(nx4 + 255) / 256, 256, 0, stream>>>(
        x, wmu, wrho, ew, bmu, brho, eb, xb, wb, bs, nx4, nw4, Nout);

    dim3 grid((M / 256) * (Nout / 128));
    gemm_bk32<<<grid, 512, 0, stream>>>(xb, wb, bs, out, M, Nout, K);
}

// Round 9
// 567.438 us; speedup vs baseline: 1.2530x; 1.2530x over previous
//
#include <hip/hip_runtime.h>
#include <hip/hip_bf16.h>

typedef unsigned short u16;
typedef __attribute__((ext_vector_type(4))) float f32x4;
typedef __attribute__((ext_vector_type(8))) short bf16x8;

// ---------------------------------------------------------------------------
// helpers
// ---------------------------------------------------------------------------
__device__ __forceinline__ u16 f2bf(float f) {
    union { float f; unsigned u; } v; v.f = f;
    unsigned r = (v.u + 0x7fffu + ((v.u >> 16) & 1u)) >> 16;   // RNE
    return (u16)r;
}

__device__ __forceinline__ float softplus(float x) {
    return (x > 15.f) ? x : log1pf(__expf(x));
}

__device__ __forceinline__ void gload_lds16(const void* g, void* l) {
    __builtin_amdgcn_global_load_lds(
        (__attribute__((address_space(1))) void*)(g),
        (__attribute__((address_space(3))) void*)(l),
        16, 0, 0);
}

#define BAR() do { asm volatile("" ::: "memory"); \
                   __builtin_amdgcn_s_barrier();  \
                   asm volatile("" ::: "memory"); } while (0)

// inline-asm ds_read_b128 with compile-time immediate offset (invisible to
// alias analysis -> no compiler-inserted vmcnt drains vs the DMA writes)
#define DSR(dst, base, off) \
    asm volatile("ds_read_b128 %0, %1 offset:%2" : "=v"(dst) : "v"(base), "i"(off))

// wait for all ds_reads, then pin the following MFMA cluster (rule #18:
// hipcc hoists register-only MFMA past inline-asm lgkmcnt otherwise)
#define LGKM0_FENCE() do { \
    asm volatile("s_waitcnt lgkmcnt(0)" ::: "memory"); \
    __builtin_amdgcn_sched_barrier(0); } while (0)

// ---------------------------------------------------------------------------
// fused prep: x->bf16, W = mu + softplus(rho)*eps -> bf16, bias (f32)
// ---------------------------------------------------------------------------
__global__ __launch_bounds__(256) void prep_all(
        const float* __restrict__ x,
        const float* __restrict__ wmu, const float* __restrict__ wrho,
        const float* __restrict__ ew,
        const float* __restrict__ bmu, const float* __restrict__ brho,
        const float* __restrict__ eb,
        u16* __restrict__ xb, u16* __restrict__ wb, float* __restrict__ bs,
        int nx4, int nw4, int nb) {
    int i = blockIdx.x * 256 + threadIdx.x;
    if (i < nx4) {
        float4 v = ((const float4*)x)[i];
        ushort4 o;
        o.x = f2bf(v.x); o.y = f2bf(v.y); o.z = f2bf(v.z); o.w = f2bf(v.w);
        ((ushort4*)xb)[i] = o;
    }
    if (i < nw4) {
        float4 m = ((const float4*)wmu)[i];
        float4 r = ((const float4*)wrho)[i];
        float4 e = ((const float4*)ew)[i];
        ushort4 o;
        o.x = f2bf(m.x + softplus(r.x) * e.x);
        o.y = f2bf(m.y + softplus(r.y) * e.y);
        o.z = f2bf(m.z + softplus(r.z) * e.z);
        o.w = f2bf(m.w + softplus(r.w) * e.w);
        ((ushort4*)wb)[i] = o;
    }
    if (i < nb) {
        bs[i] = bmu[i] + softplus(brho[i]) * eb[i];
    }
}

// ---------------------------------------------------------------------------
// 256x256 8-phase bf16 GEMM (B^T) + bias — round-3 schedule (best: 477 us,
// 0 conflicts), fragment reads converted to inline-asm ds_read_b128 and
// MFMA clusters pinned with sched_barrier(0) after each lgkmcnt(0).
// LDS: A0|B0|A1|B1 at +0|+32K|+64K|+96K, [256][64] bf16 each half-pair,
// chunk-XOR swizzle kc ^= row&7 (row multiple of 16 => kc ^= lane&7).
// ---------------------------------------------------------------------------
template <int MB, int NB>
__device__ __forceinline__ void mfma_quad(f32x4 (&acc)[8][4],
                                          const bf16x8 (&av)[4][2],
                                          const bf16x8 (&bv)[2][2]) {
#pragma unroll
    for (int ks = 0; ks < 2; ++ks)
#pragma unroll
        for (int mi = 0; mi < 4; ++mi)
#pragma unroll
            for (int ni = 0; ni < 2; ++ni)
                acc[MB + mi][NB + ni] = __builtin_amdgcn_mfma_f32_16x16x32_bf16(
                    av[mi][ks], bv[ni][ks], acc[MB + mi][NB + ni], 0, 0, 0);
}

#define STAGE(region, h, P, koff) do {                                          \
    gload_lds16(P[h][0] + (koff), (char*)(region) + (h) * 16384 + (w * 2 + 0) * 1024); \
    gload_lds16(P[h][1] + (koff), (char*)(region) + (h) * 16384 + (w * 2 + 1) * 1024); \
} while (0)

// A fragment block: 8 reads (4 mi x 2 ks). Rbyte: A0=0, A1=65536. roff: 0/64.
#define RD_A(Rbyte, roff) do {                                         \
    unsigned r0a = aB0 + ((Rbyte) + (roff) * 128);                     \
    unsigned r1a = aB1 + ((Rbyte) + (roff) * 128);                     \
    DSR(a[0][0], r0a, 0);    DSR(a[0][1], r1a, 0);                     \
    DSR(a[1][0], r0a, 2048); DSR(a[1][1], r1a, 2048);                  \
    DSR(a[2][0], r0a, 4096); DSR(a[2][1], r1a, 4096);                  \
    DSR(a[3][0], r0a, 6144); DSR(a[3][1], r1a, 6144); } while (0)

// B fragment block: 4 reads (2 ni x 2 ks). Rbyte: B0=32768, B1=98304. roff: 0/32.
#define RD_B(dst, Rbyte, roff) do {                                    \
    unsigned r0b = bB0 + ((Rbyte) + (roff) * 128);                     \
    unsigned r1b = bB1 + ((Rbyte) + (roff) * 128);                     \
    DSR(dst[0][0], r0b, 0);    DSR(dst[0][1], r1b, 0);                 \
    DSR(dst[1][0], r0b, 2048); DSR(dst[1][1], r1b, 2048); } while (0)

__global__ __launch_bounds__(512, 2) void gemm256_8ph(
        const u16* __restrict__ A,   // [M][K] bf16
        const u16* __restrict__ B,   // [Nout][K] bf16
        const float* __restrict__ bias,
        float* __restrict__ C,       // [M][Nout] fp32
        int M, int Nout, int K) {
    __shared__ __attribute__((aligned(16))) u16 smem[4][16384];  // A0,B0,A1,B1

    const int tid  = threadIdx.x;
    const int lane = tid & 63;
    const int w    = tid >> 6;     // wave 0..7
    const int wr   = w >> 2;       // 0..1 -> 128-row slice
    const int wc   = w & 3;        // 0..3 -> 64-col slice

    u16* A0 = smem[0]; u16* B0 = smem[1];
    u16* A1 = smem[2]; u16* B1 = smem[3];

    // bijective XCD swizzle (nwg % 8 == 0 here)
    const int nbn = Nout >> 8;
    const int nwg = (M >> 8) * nbn;
    const int cpx = nwg >> 3;
    const int swz = ((int)blockIdx.x & 7) * cpx + ((int)blockIdx.x >> 3);
    const int m0 = (swz / nbn) << 8;
    const int n0 = (swz % nbn) << 8;

    // per-thread staging source pointers (inverse-swizzled global chunks)
    const u16* PA[2][2]; const u16* PB[2][2];
#pragma unroll
    for (int q = 0; q < 2; ++q) {
        int c   = (w * 2 + q) * 64 + lane;
        int row = c >> 3;
        int kc  = (c & 7) ^ (row & 7);
#pragma unroll
        for (int h = 0; h < 2; ++h) {
            PA[h][q] = A + (size_t)(m0 + h * 128 + row) * K + kc * 8;
            PB[h][q] = B + (size_t)(n0 + h * 128 + row) * K + kc * 8;
        }
    }

    // fragment-read lane constants: row_local = lane&15 (r0 multiple of 16),
    // kc(ks) = (ks*4 + (lane>>4)) ^ (lane&7); byte = row*128 + kc*16
    const unsigned sb    = (unsigned)(size_t)(void*)&smem[0][0];
    const unsigned loff0 = (unsigned)((lane & 15) * 128 + (((lane >> 4) ^ (lane & 7)) & 7) * 16);
    const unsigned loff1 = (unsigned)((lane & 15) * 128 + ((((lane >> 4) + 4) ^ (lane & 7)) & 7) * 16);
    const unsigned aB0 = sb + (unsigned)(wr * 128 * 128) + loff0;
    const unsigned aB1 = sb + (unsigned)(wr * 128 * 128) + loff1;
    const unsigned bB0 = sb + (unsigned)(wc * 64 * 128) + loff0;
    const unsigned bB1 = sb + (unsigned)(wc * 64 * 128) + loff1;

    bf16x8 a[4][2], bl[2][2], bh[2][2];
    f32x4 acc[8][4] = {};

    const int NT = K >> 6;    // K-tiles
    const int NI = NT >> 1;   // iterations (2 tiles each)

    // prologue: tile0 -> buf0 (all), tile1 -> buf1 (B units)
    STAGE(B0, 0, PB, 0);  STAGE(B0, 1, PB, 0);
    STAGE(A0, 0, PA, 0);  STAGE(A0, 1, PA, 0);
    STAGE(B1, 0, PB, 64); STAGE(B1, 1, PB, 64);
    asm volatile("s_waitcnt vmcnt(4)" ::: "memory");   // tile0 landed
    BAR();
    RD_A(0, 0);   // al pre-read for PH1 (matches PH8-exit state)

#pragma unroll 1
    for (int i = 0; i < NI; ++i) {
        int t2 = 2 * i + 2; if (t2 >= NT) t2 -= NT;
        int t3 = 2 * i + 3; if (t3 >= NT) t3 -= NT;
        const int k1 = (2 * i + 1) << 6;
        const int k2 = t2 << 6;
        const int k3 = t3 << 6;

        // -------- PH1: q0 = al x bl          | reads bl(4) | stage A1-lo(t1)
        RD_B(bl, 32768, 0);
        STAGE(A1, 0, PA, k1);
        BAR();
        LGKM0_FENCE();
        __builtin_amdgcn_s_setprio(1);
        mfma_quad<0, 0>(acc, a, bl);
        __builtin_amdgcn_s_setprio(0);
        BAR();

        // -------- PH2: q1 = al x bh          | reads bh(4) | stage A1-hi(t1)
        RD_B(bh, 32768, 32);
        STAGE(A1, 1, PA, k1);
        BAR();
        LGKM0_FENCE();
        __builtin_amdgcn_s_setprio(1);
        mfma_quad<0, 2>(acc, a, bh);
        __builtin_amdgcn_s_setprio(0);
        BAR();

        // -------- PH3: q2 = ah x bh          | reads ah(8) | stage B0-lo(t2)
        RD_A(0, 64);
        STAGE(B0, 0, PB, k2);
        BAR();
        LGKM0_FENCE();
        __builtin_amdgcn_s_setprio(1);
        mfma_quad<4, 2>(acc, a, bh);
        __builtin_amdgcn_s_setprio(0);
        BAR();

        // -------- PH4: q3 = ah x bl | stage B0-hi(t2) | vmcnt(4): t1 landed
        //          then read al'(8) from A1 (hidden under q3's MFMA drain)
        STAGE(B0, 1, PB, k2);
        asm volatile("s_waitcnt vmcnt(4)" ::: "memory");
        BAR();
        __builtin_amdgcn_s_setprio(1);
        mfma_quad<4, 0>(acc, a, bl);
        __builtin_amdgcn_s_setprio(0);
        RD_A(65536, 0);
        BAR();

        // -------- PH5: q0' = al' x bl'       | reads bl'(4) | stage A0-lo(t2)
        RD_B(bl, 98304, 0);
        STAGE(A0, 0, PA, k2);
        BAR();
        LGKM0_FENCE();
        __builtin_amdgcn_s_setprio(1);
        mfma_quad<0, 0>(acc, a, bl);
        __builtin_amdgcn_s_setprio(0);
        BAR();

        // -------- PH6: q1' = al' x bh'       | reads bh'(4) | stage A0-hi(t2)
        RD_B(bh, 98304, 32);
        STAGE(A0, 1, PA, k2);
        BAR();
        LGKM0_FENCE();
        __builtin_amdgcn_s_setprio(1);
        mfma_quad<0, 2>(acc, a, bh);
        __builtin_amdgcn_s_setprio(0);
        BAR();

        // -------- PH7: q2' = ah' x bh'       | reads ah'(8) | stage B1-lo(t3)
        RD_A(65536, 64);
        STAGE(B1, 0, PB, k3);
        BAR();
        LGKM0_FENCE();
        __builtin_amdgcn_s_setprio(1);
        mfma_quad<4, 2>(acc, a, bh);
        __builtin_amdgcn_s_setprio(0);
        BAR();

        // -------- PH8: q3' = ah' x bl' | stage B1-hi(t3) | vmcnt(4): t2 landed
        //          then read al''(8) from A0 for next iteration's PH1
        STAGE(B1, 1, PB, k3);
        asm volatile("s_waitcnt vmcnt(4)" ::: "memory");
        BAR();
        __builtin_amdgcn_s_setprio(1);
        mfma_quad<4, 0>(acc, a, bl);
        __builtin_amdgcn_s_setprio(0);
        RD_A(0, 0);
        BAR();
    }

    asm volatile("s_waitcnt vmcnt(0) lgkmcnt(0)" ::: "memory");  // drain

    // epilogue: C/D layout col = lane&15, row = (lane>>4)*4 + q
    const int crow = (lane >> 4) * 4;
    const int ccol = lane & 15;
#pragma unroll
    for (int mi = 0; mi < 8; ++mi) {
#pragma unroll
        for (int ni = 0; ni < 4; ++ni) {
            const int row = m0 + wr * 128 + mi * 16 + crow;
            const int col = n0 + wc * 64 + ni * 16 + ccol;
            const float bv = bias[col];
            float* Cp = C + (size_t)row * Nout + col;
#pragma unroll
            for (int q = 0; q < 4; ++q)
                Cp[(size_t)q * Nout] = acc[mi][ni][q] + bv;
        }
    }
}

// ---------------------------------------------------------------------------
// launch
// ---------------------------------------------------------------------------
extern "C" void kernel_launch(void* const* d_in, const int* in_sizes, int n_in,
                              void* d_out, int out_size, void* d_ws, size_t ws_size,
                              hipStream_t stream) {
    const float* x    = (const float*)d_in[0];
    const float* wmu  = (const float*)d_in[1];
    const float* wrho = (const float*)d_in[2];
    const float* bmu  = (const float*)d_in[3];
    const float* brho = (const float*)d_in[4];
    const float* ew   = (const float*)d_in[5];
    const float* eb   = (const float*)d_in[6];
    float* out = (float*)d_out;

    const int Nout = in_sizes[3];            // 4096
    const int K    = in_sizes[1] / Nout;     // 4096
    const int M    = in_sizes[0] / K;        // 16384

    u16* xb = (u16*)d_ws;
    u16* wb = xb + (size_t)M * K;
    float* bs = (float*)(wb + (size_t)Nout * K);

    const int nx4 = (M * K) / 4;
    const int nw4 = (Nout * K) / 4;
    prep_all<<<(nx4 + 255) / 256, 256, 0, stream>>>(
        x, wmu, wrho, ew, bmu, brho, eb, xb, wb, bs, nx4, nw4, Nout);

    dim3 grid((M / 256) * (Nout / 256));
    gemm256_8ph<<<grid, 512, 0, stream>>>(xb, wb, bs, out, M, Nout, K);
}

// Round 10
// 567.427 us; speedup vs baseline: 1.2531x; 1.0000x over previous
//
#include <hip/hip_runtime.h>
#include <hip/hip_bf16.h>

typedef unsigned short u16;
typedef __attribute__((ext_vector_type(4))) float f32x4;
typedef __attribute__((ext_vector_type(8))) short bf16x8;

// ---------------------------------------------------------------------------
// helpers
// ---------------------------------------------------------------------------
__device__ __forceinline__ u16 f2bf(float f) {
    union { float f; unsigned u; } v; v.f = f;
    unsigned r = (v.u + 0x7fffu + ((v.u >> 16) & 1u)) >> 16;   // RNE
    return (u16)r;
}

__device__ __forceinline__ float softplus(float x) {
    return (x > 15.f) ? x : log1pf(__expf(x));
}

__device__ __forceinline__ void gload_lds16(const void* g, void* l) {
    __builtin_amdgcn_global_load_lds(
        (__attribute__((address_space(1))) void*)(g),
        (__attribute__((address_space(3))) void*)(l),
        16, 0, 0);
}

#define BAR() do { asm volatile("" ::: "memory"); \
                   __builtin_amdgcn_s_barrier();  \
                   asm volatile("" ::: "memory"); } while (0)

// inline-asm ds_read_b128 with compile-time immediate offset
#define DSR(dst, base, off) \
    asm volatile("ds_read_b128 %0, %1 offset:%2" : "=v"(dst) : "v"(base), "i"(off))

// counted lgkm gate + scheduler fence (rule #18: MFMA must not hoist past it)
#define LGKM(n) do { \
    asm volatile("s_waitcnt lgkmcnt(" #n ")" ::: "memory"); \
    __builtin_amdgcn_sched_barrier(0); } while (0)

// ---------------------------------------------------------------------------
// fused prep: x->bf16, W = mu + softplus(rho)*eps -> bf16, bias (f32)
// ---------------------------------------------------------------------------
__global__ __launch_bounds__(256) void prep_all(
        const float* __restrict__ x,
        const float* __restrict__ wmu, const float* __restrict__ wrho,
        const float* __restrict__ ew,
        const float* __restrict__ bmu, const float* __restrict__ brho,
        const float* __restrict__ eb,
        u16* __restrict__ xb, u16* __restrict__ wb, float* __restrict__ bs,
        int nx4, int nw4, int nb) {
    int i = blockIdx.x * 256 + threadIdx.x;
    if (i < nx4) {
        float4 v = ((const float4*)x)[i];
        ushort4 o;
        o.x = f2bf(v.x); o.y = f2bf(v.y); o.z = f2bf(v.z); o.w = f2bf(v.w);
        ((ushort4*)xb)[i] = o;
    }
    if (i < nw4) {
        float4 m = ((const float4*)wmu)[i];
        float4 r = ((const float4*)wrho)[i];
        float4 e = ((const float4*)ew)[i];
        ushort4 o;
        o.x = f2bf(m.x + softplus(r.x) * e.x);
        o.y = f2bf(m.y + softplus(r.y) * e.y);
        o.z = f2bf(m.z + softplus(r.z) * e.z);
        o.w = f2bf(m.w + softplus(r.w) * e.w);
        ((ushort4*)wb)[i] = o;
    }
    if (i < nb) {
        bs[i] = bmu[i] + softplus(brho[i]) * eb[i];
    }
}

// ---------------------------------------------------------------------------
// 256x256 8-phase bf16 GEMM (B^T) + bias — round-3 schedule + ks-split
// partial lgkm gating: each phase's DSR block is ordered ks-major and the
// 16-MFMA cluster is split into two 8-MFMA halves gated by lgkmcnt(2)/(4)
// then lgkmcnt(0), so the ks=0 half starts as soon as its own reads land
// and the ks=1 reads drain UNDER it (DS ops retire in order).
// LDS: A0|B0|A1|B1 at +0|+32K|+64K|+96K, chunk-XOR swizzle kc ^= row&7.
// ---------------------------------------------------------------------------
template <int MB, int NB, int KS>
__device__ __forceinline__ void mfma_half(f32x4 (&acc)[8][4],
                                          const bf16x8 (&av)[4][2],
                                          const bf16x8 (&bv)[2][2]) {
#pragma unroll
    for (int mi = 0; mi < 4; ++mi)
#pragma unroll
        for (int ni = 0; ni < 2; ++ni)
            acc[MB + mi][NB + ni] = __builtin_amdgcn_mfma_f32_16x16x32_bf16(
                av[mi][KS], bv[ni][KS], acc[MB + mi][NB + ni], 0, 0, 0);
}

template <int MB, int NB>
__device__ __forceinline__ void mfma_quad(f32x4 (&acc)[8][4],
                                          const bf16x8 (&av)[4][2],
                                          const bf16x8 (&bv)[2][2]) {
    mfma_half<MB, NB, 0>(acc, av, bv);
    mfma_half<MB, NB, 1>(acc, av, bv);
}

#define STAGE(region, h, P, koff) do {                                          \
    gload_lds16(P[h][0] + (koff), (char*)(region) + (h) * 16384 + (w * 2 + 0) * 1024); \
    gload_lds16(P[h][1] + (koff), (char*)(region) + (h) * 16384 + (w * 2 + 1) * 1024); \
} while (0)

// A fragment block, ks-major: 4x ks=0 reads first, then 4x ks=1.
#define RD_A(Rbyte, roff) do {                                         \
    unsigned r0a = aB0 + ((Rbyte) + (roff) * 128);                     \
    unsigned r1a = aB1 + ((Rbyte) + (roff) * 128);                     \
    DSR(a[0][0], r0a, 0);    DSR(a[1][0], r0a, 2048);                  \
    DSR(a[2][0], r0a, 4096); DSR(a[3][0], r0a, 6144);                  \
    DSR(a[0][1], r1a, 0);    DSR(a[1][1], r1a, 2048);                  \
    DSR(a[2][1], r1a, 4096); DSR(a[3][1], r1a, 6144); } while (0)

// B fragment block, ks-major: 2x ks=0 first, then 2x ks=1.
#define RD_B(dst, Rbyte, roff) do {                                    \
    unsigned r0b = bB0 + ((Rbyte) + (roff) * 128);                     \
    unsigned r1b = bB1 + ((Rbyte) + (roff) * 128);                     \
    DSR(dst[0][0], r0b, 0);    DSR(dst[1][0], r0b, 2048);              \
    DSR(dst[0][1], r1b, 0);    DSR(dst[1][1], r1b, 2048); } while (0)

__global__ __launch_bounds__(512, 2) void gemm256_8ph(
        const u16* __restrict__ A,   // [M][K] bf16
        const u16* __restrict__ B,   // [Nout][K] bf16
        const float* __restrict__ bias,
        float* __restrict__ C,       // [M][Nout] fp32
        int M, int Nout, int K) {
    __shared__ __attribute__((aligned(16))) u16 smem[4][16384];  // A0,B0,A1,B1

    const int tid  = threadIdx.x;
    const int lane = tid & 63;
    const int w    = tid >> 6;     // wave 0..7
    const int wr   = w >> 2;       // 0..1 -> 128-row slice
    const int wc   = w & 3;        // 0..3 -> 64-col slice

    u16* A0 = smem[0]; u16* B0 = smem[1];
    u16* A1 = smem[2]; u16* B1 = smem[3];

    // bijective XCD swizzle (nwg % 8 == 0 here)
    const int nbn = Nout >> 8;
    const int nwg = (M >> 8) * nbn;
    const int cpx = nwg >> 3;
    const int swz = ((int)blockIdx.x & 7) * cpx + ((int)blockIdx.x >> 3);
    const int m0 = (swz / nbn) << 8;
    const int n0 = (swz % nbn) << 8;

    // per-thread staging source pointers (inverse-swizzled global chunks)
    const u16* PA[2][2]; const u16* PB[2][2];
#pragma unroll
    for (int q = 0; q < 2; ++q) {
        int c   = (w * 2 + q) * 64 + lane;
        int row = c >> 3;
        int kc  = (c & 7) ^ (row & 7);
#pragma unroll
        for (int h = 0; h < 2; ++h) {
            PA[h][q] = A + (size_t)(m0 + h * 128 + row) * K + kc * 8;
            PB[h][q] = B + (size_t)(n0 + h * 128 + row) * K + kc * 8;
        }
    }

    // fragment-read lane constants: row_local = lane&15,
    // kc(ks) = (ks*4 + (lane>>4)) ^ (lane&7); byte = row*128 + kc*16
    const unsigned sb    = (unsigned)(size_t)(void*)&smem[0][0];
    const unsigned loff0 = (unsigned)((lane & 15) * 128 + (((lane >> 4) ^ (lane & 7)) & 7) * 16);
    const unsigned loff1 = (unsigned)((lane & 15) * 128 + ((((lane >> 4) + 4) ^ (lane & 7)) & 7) * 16);
    const unsigned aB0 = sb + (unsigned)(wr * 128 * 128) + loff0;
    const unsigned aB1 = sb + (unsigned)(wr * 128 * 128) + loff1;
    const unsigned bB0 = sb + (unsigned)(wc * 64 * 128) + loff0;
    const unsigned bB1 = sb + (unsigned)(wc * 64 * 128) + loff1;

    bf16x8 a[4][2], bl[2][2], bh[2][2];
    f32x4 acc[8][4] = {};

    const int NT = K >> 6;    // K-tiles
    const int NI = NT >> 1;   // iterations (2 tiles each)

    // prologue: tile0 -> buf0 (all), tile1 -> buf1 (B units)
    STAGE(B0, 0, PB, 0);  STAGE(B0, 1, PB, 0);
    STAGE(A0, 0, PA, 0);  STAGE(A0, 1, PA, 0);
    STAGE(B1, 0, PB, 64); STAGE(B1, 1, PB, 64);
    asm volatile("s_waitcnt vmcnt(4)" ::: "memory");   // tile0 landed
    BAR();
    RD_A(0, 0);   // al pre-read for PH1 (8 reads outstanding, matches PH8 exit)

#pragma unroll 1
    for (int i = 0; i < NI; ++i) {
        int t2 = 2 * i + 2; if (t2 >= NT) t2 -= NT;
        int t3 = 2 * i + 3; if (t3 >= NT) t3 -= NT;
        const int k1 = (2 * i + 1) << 6;
        const int k2 = t2 << 6;
        const int k3 = t3 << 6;

        // ---- PH1: q0 = al x bl | reads bl(4, ks-major) | stage A1-lo(t1)
        //      gate ks0 at lgkm(2) (drains 8 A-reads + bl[*][0]); ks1 at 0
        RD_B(bl, 32768, 0);
        STAGE(A1, 0, PA, k1);
        BAR();
        __builtin_amdgcn_s_setprio(1);
        LGKM(2);
        mfma_half<0, 0, 0>(acc, a, bl);
        LGKM(0);
        mfma_half<0, 0, 1>(acc, a, bl);
        __builtin_amdgcn_s_setprio(0);
        BAR();

        // ---- PH2: q1 = al x bh | reads bh(4) | stage A1-hi(t1)
        RD_B(bh, 32768, 32);
        STAGE(A1, 1, PA, k1);
        BAR();
        __builtin_amdgcn_s_setprio(1);
        LGKM(2);
        mfma_half<0, 2, 0>(acc, a, bh);
        LGKM(0);
        mfma_half<0, 2, 1>(acc, a, bh);
        __builtin_amdgcn_s_setprio(0);
        BAR();

        // ---- PH3: q2 = ah x bh | reads ah(8, ks-major) | stage B0-lo(t2)
        RD_A(0, 64);
        STAGE(B0, 0, PB, k2);
        BAR();
        __builtin_amdgcn_s_setprio(1);
        LGKM(4);
        mfma_half<4, 2, 0>(acc, a, bh);
        LGKM(0);
        mfma_half<4, 2, 1>(acc, a, bh);
        __builtin_amdgcn_s_setprio(0);
        BAR();

        // ---- PH4: q3 = ah x bl | stage B0-hi(t2) | vmcnt(4): t1 landed
        //      operands resident (no gate); trailing al'(8) read from A1
        STAGE(B0, 1, PB, k2);
        asm volatile("s_waitcnt vmcnt(4)" ::: "memory");
        BAR();
        __builtin_amdgcn_s_setprio(1);
        mfma_quad<4, 0>(acc, a, bl);
        __builtin_amdgcn_s_setprio(0);
        RD_A(65536, 0);
        BAR();

        // ---- PH5: q0' = al' x bl' | reads bl'(4) | stage A0-lo(t2)
        RD_B(bl, 98304, 0);
        STAGE(A0, 0, PA, k2);
        BAR();
        __builtin_amdgcn_s_setprio(1);
        LGKM(2);
        mfma_half<0, 0, 0>(acc, a, bl);
        LGKM(0);
        mfma_half<0, 0, 1>(acc, a, bl);
        __builtin_amdgcn_s_setprio(0);
        BAR();

        // ---- PH6: q1' = al' x bh' | reads bh'(4) | stage A0-hi(t2)
        RD_B(bh, 98304, 32);
        STAGE(A0, 1, PA, k2);
        BAR();
        __builtin_amdgcn_s_setprio(1);
        LGKM(2);
        mfma_half<0, 2, 0>(acc, a, bh);
        LGKM(0);
        mfma_half<0, 2, 1>(acc, a, bh);
        __builtin_amdgcn_s_setprio(0);
        BAR();

        // ---- PH7: q2' = ah' x bh' | reads ah'(8) | stage B1-lo(t3)
        RD_A(65536, 64);
        STAGE(B1, 0, PB, k3);
        BAR();
        __builtin_amdgcn_s_setprio(1);
        LGKM(4);
        mfma_half<4, 2, 0>(acc, a, bh);
        LGKM(0);
        mfma_half<4, 2, 1>(acc, a, bh);
        __builtin_amdgcn_s_setprio(0);
        BAR();

        // ---- PH8: q3' = ah' x bl' | stage B1-hi(t3) | vmcnt(4): t2 landed
        //      trailing al''(8) read from A0 for next PH1
        STAGE(B1, 1, PB, k3);
        asm volatile("s_waitcnt vmcnt(4)" ::: "memory");
        BAR();
        __builtin_amdgcn_s_setprio(1);
        mfma_quad<4, 0>(acc, a, bl);
        __builtin_amdgcn_s_setprio(0);
        RD_A(0, 0);
        BAR();
    }

    asm volatile("s_waitcnt vmcnt(0) lgkmcnt(0)" ::: "memory");  // drain

    // epilogue: C/D layout col = lane&15, row = (lane>>4)*4 + q
    const int crow = (lane >> 4) * 4;
    const int ccol = lane & 15;
#pragma unroll
    for (int mi = 0; mi < 8; ++mi) {
#pragma unroll
        for (int ni = 0; ni < 4; ++ni) {
            const int row = m0 + wr * 128 + mi * 16 + crow;
            const int col = n0 + wc * 64 + ni * 16 + ccol;
            const float bv = bias[col];
            float* Cp = C + (size_t)row * Nout + col;
#pragma unroll
            for (int q = 0; q < 4; ++q)
                Cp[(size_t)q * Nout] = acc[mi][ni][q] + bv;
        }
    }
}

// ---------------------------------------------------------------------------
// launch
// ---------------------------------------------------------------------------
extern "C" void kernel_launch(void* const* d_in, const int* in_sizes, int n_in,
                              void* d_out, int out_size, void* d_ws, size_t ws_size,
                              hipStream_t stream) {
    const float* x    = (const float*)d_in[0];
    const float* wmu  = (const float*)d_in[1];
    const float* wrho = (const float*)d_in[2];
    const float* bmu  = (const float*)d_in[3];
    const float* brho = (const float*)d_in[4];
    const float* ew   = (const float*)d_in[5];
    const float* eb   = (const float*)d_in[6];
    float* out = (float*)d_out;

    const int Nout = in_sizes[3];            // 4096
    const int K    = in_sizes[1] / Nout;     // 4096
    const int M    = in_sizes[0] / K;        // 16384

    u16* xb = (u16*)d_ws;
    u16* wb = xb + (size_t)M * K;
    float* bs = (float*)(wb + (size_t)Nout * K);

    const int nx4 = (M * K) / 4;
    const int nw4 = (Nout * K) / 4;
    prep_all<<<(nx4 + 255) / 256, 256, 0, stream>>>(
        x, wmu, wrho, ew, bmu, brho, eb, xb, wb, bs, nx4, nw4, Nout);

    dim3 grid((M / 256) * (Nout / 256));
    gemm256_8ph<<<grid, 512, 0, stream>>>(xb, wb, bs, out, M, Nout, K);
}